// Round 2
// baseline (2283.850 us; speedup 1.0000x reference)
//
#include <hip/hip_runtime.h>
#include <stdint.h>

#define B_  16
#define QL  2048
#define KL  2048
#define FD  128

// One block = one (b, 8 q-rows) tile, 256 threads (4 waves).
// Phase 2: thread owns 8 contiguous k-cols x all 8 q-rows (64 fp32 accums).
// Phase 5: thread owns an f-octet x 1/16th of K; LDS reduce across segments.
__global__ __launch_bounds__(256) void alibi_attn(
    const float* __restrict__ qp,
    const float* __restrict__ kp,
    const float* __restrict__ vp,
    const float* __restrict__ cqp,
    const float* __restrict__ ckp,
    const int* __restrict__ amp,
    const int* __restrict__ almp,
    const float* __restrict__ bsp,
    const float* __restrict__ rmp,
    float* __restrict__ outp)
{
  __shared__ float q_l[8 * FD];        // 4 KB fp32 [r][f]
  __shared__ float c_l[KL * 8];        // 64 KB fp32 [k][r]
  __shared__ float cq_l[16];
  __shared__ float redw[4 * 8];
  __shared__ float l_l[8];
  __shared__ float red2[256 * 8];      // 8 KB phase-5 reduction

  const int t   = threadIdx.x;
  const int bid = blockIdx.x;
  const int b   = bid >> 8;            // 256 q-tiles per batch
  const int q0  = (bid & 255) << 3;

  const float bscale = bsp[0] / rmp[0];
  const float scale  = 0.08838834764831845f;   // 128^-0.5

  // ---- Phase 1: stage Q rows + coords_q into LDS ----
  {
    const long long qbase = ((long long)(b * QL + q0)) * FD;
    float4 u = ((const float4*)(qp + qbase))[t];   // 4 floats/thread = 4 KB
    float* dst = &q_l[t * 4];
    dst[0] = u.x; dst[1] = u.y; dst[2] = u.z; dst[3] = u.w;
    if (t < 16) cq_l[t] = cqp[(long long)(b * QL + q0) * 2 + t];
  }
  __syncthreads();

  // ---- Phase 2: S = Q K^T (8 rows x 8 k-cols per thread) ----
  float s[8][8];
  #pragma unroll
  for (int r = 0; r < 8; ++r)
    #pragma unroll
    for (int kk = 0; kk < 8; ++kk) s[r][kk] = 0.f;

  const int k0 = t * 8;
  const long long kbase = ((long long)(b * KL) + k0) * FD;
  for (int fc = 0; fc < FD / 4; ++fc) {
    float qv[8][4];
    #pragma unroll
    for (int r = 0; r < 8; ++r) {
      float4 qq = *(const float4*)&q_l[r * FD + fc * 4];
      qv[r][0] = qq.x; qv[r][1] = qq.y; qv[r][2] = qq.z; qv[r][3] = qq.w;
    }
    #pragma unroll
    for (int kk = 0; kk < 8; ++kk) {
      float4 kb = *(const float4*)(kp + kbase + kk * FD + fc * 4);
      #pragma unroll
      for (int r = 0; r < 8; ++r) {
        s[r][kk] = fmaf(qv[r][0], kb.x, s[r][kk]);
        s[r][kk] = fmaf(qv[r][1], kb.y, s[r][kk]);
        s[r][kk] = fmaf(qv[r][2], kb.z, s[r][kk]);
        s[r][kk] = fmaf(qv[r][3], kb.w, s[r][kk]);
      }
    }
  }

  // ---- Phase 3: softmax denominators (no max-subtract; |s*scale| <~ 7) ----
  float lsum[8];
  #pragma unroll
  for (int r = 0; r < 8; ++r) {
    lsum[r] = 0.f;
    #pragma unroll
    for (int kk = 0; kk < 8; ++kk) {
      float e = __expf(s[r][kk] * scale);
      s[r][kk] = e;
      lsum[r] += e;
    }
  }
  #pragma unroll
  for (int off = 32; off > 0; off >>= 1) {
    #pragma unroll
    for (int r = 0; r < 8; ++r) lsum[r] += __shfl_down(lsum[r], off, 64);
  }
  const int lane = t & 63, wv = t >> 6;
  if (lane == 0) {
    #pragma unroll
    for (int r = 0; r < 8; ++r) redw[wv * 8 + r] = lsum[r];
  }
  __syncthreads();
  if (t < 8) {
    float l = redw[t] + redw[8 + t] + redw[16 + t] + redw[24 + t];
    l_l[t] = 1.0f / l;
  }
  __syncthreads();

  // ---- Phase 4: c[r][k] = !attn * (e/l - !alibi * dist*bscale) -> LDS ----
  float ckx[8], cky[8];
  {
    const float* cb = ckp + (long long)(b * KL + k0) * 2;   // 8 k x 2 coords
    float4 a0 = *(const float4*)cb;
    float4 a1 = *(const float4*)(cb + 4);
    float4 a2 = *(const float4*)(cb + 8);
    float4 a3 = *(const float4*)(cb + 12);
    ckx[0] = a0.x; cky[0] = a0.y; ckx[1] = a0.z; cky[1] = a0.w;
    ckx[2] = a1.x; cky[2] = a1.y; ckx[3] = a1.z; cky[3] = a1.w;
    ckx[4] = a2.x; cky[4] = a2.y; ckx[5] = a2.z; cky[5] = a2.w;
    ckx[6] = a3.x; cky[6] = a3.y; ckx[7] = a3.z; cky[7] = a3.w;
  }
  #pragma unroll
  for (int r = 0; r < 8; ++r) {
    const long long mrow = ((long long)(b * QL + q0 + r)) * KL + k0;
    int4 a0 = *(const int4*)(amp + mrow);
    int4 a1 = *(const int4*)(amp + mrow + 4);
    int4 l0 = *(const int4*)(almp + mrow);
    int4 l1 = *(const int4*)(almp + mrow + 4);
    int am8[8] = {a0.x, a0.y, a0.z, a0.w, a1.x, a1.y, a1.z, a1.w};
    int al8[8] = {l0.x, l0.y, l0.z, l0.w, l1.x, l1.y, l1.z, l1.w};
    const float cqx = cq_l[r * 2], cqy = cq_l[r * 2 + 1];
    const float linv = l_l[r];
    #pragma unroll
    for (int kk = 0; kk < 8; ++kk) {
      float w  = s[r][kk] * linv;
      float dx = cqx - ckx[kk], dy = cqy - cky[kk];
      float d  = sqrtf(fmaf(dx, dx, dy * dy)) * bscale;
      s[r][kk] = (am8[kk] != 0) ? 0.f : (w - ((al8[kk] != 0) ? 0.f : d));
    }
  }
  #pragma unroll
  for (int kk = 0; kk < 8; ++kk) {
    float4 p0, p1;
    p0.x = s[0][kk]; p0.y = s[1][kk]; p0.z = s[2][kk]; p0.w = s[3][kk];
    p1.x = s[4][kk]; p1.y = s[5][kk]; p1.z = s[6][kk]; p1.w = s[7][kk];
    *(float4*)&c_l[(k0 + kk) * 8]     = p0;
    *(float4*)&c_l[(k0 + kk) * 8 + 4] = p1;
  }
  __syncthreads();

  // ---- Phase 5: out[r][f] = sum_k c[r][k] * v[k][f] ----
  float acc[8][8];
  #pragma unroll
  for (int r = 0; r < 8; ++r)
    #pragma unroll
    for (int j = 0; j < 8; ++j) acc[r][j] = 0.f;

  const int fo  = (t & 15) * 8;   // f-octet
  const int seg = t >> 4;         // 16 segments x 128 k
  const long long vbase = ((long long)b * KL) * FD;
  for (int kk = 0; kk < 128; ++kk) {
    const int ki = seg * 128 + kk;
    float4 c0 = *(const float4*)&c_l[ki * 8];
    float4 c1 = *(const float4*)&c_l[ki * 8 + 4];
    float cr[8] = {c0.x, c0.y, c0.z, c0.w, c1.x, c1.y, c1.z, c1.w};
    const float* vrow = vp + vbase + (long long)ki * FD + fo;
    float4 v0 = *(const float4*)vrow;
    float4 v1 = *(const float4*)(vrow + 4);
    float vf[8] = {v0.x, v0.y, v0.z, v0.w, v1.x, v1.y, v1.z, v1.w};
    #pragma unroll
    for (int r = 0; r < 8; ++r)
      #pragma unroll
      for (int j = 0; j < 8; ++j)
        acc[r][j] = fmaf(cr[r], vf[j], acc[r][j]);
  }

  // reduce the 16 k-segments per (f, r) through LDS, write out
  #pragma unroll
  for (int r = 0; r < 8; ++r) {
    #pragma unroll
    for (int j = 0; j < 8; ++j) red2[t * 8 + j] = acc[r][j];
    __syncthreads();
    if (t < FD) {
      const int foi = t >> 3, j = t & 7;
      float sum = 0.f;
      #pragma unroll
      for (int sg = 0; sg < 16; ++sg) sum += red2[(sg * 16 + foi) * 8 + j];
      outp[((long long)(b * QL + q0 + r)) * FD + t] = sum;
    }
    __syncthreads();
  }
}

extern "C" void kernel_launch(void* const* d_in, const int* in_sizes, int n_in,
                              void* d_out, int out_size, void* d_ws, size_t ws_size,
                              hipStream_t stream) {
  const float* q   = (const float*)d_in[0];
  const float* k   = (const float*)d_in[1];
  const float* v   = (const float*)d_in[2];
  const float* cq  = (const float*)d_in[3];
  const float* ck  = (const float*)d_in[4];
  const int*   am  = (const int*)d_in[5];
  const int*   alm = (const int*)d_in[6];
  const float* bs  = (const float*)d_in[7];
  const float* rm  = (const float*)d_in[8];
  float*       out = (float*)d_out;

  dim3 grid(B_ * (QL / 8));   // 4096 blocks; consecutive blocks share batch b
  dim3 block(256);
  hipLaunchKernelGGL(alibi_attn, grid, block, 0, stream,
                     q, k, v, cq, ck, am, alm, bs, rm, out);
}

// Round 3
// 751.932 us; speedup vs baseline: 3.0373x; 3.0373x over previous
//
#include <hip/hip_runtime.h>
#include <stdint.h>

#define B_  16
#define QL  2048
#define KL  2048
#define FD  128
#define BQ  64      // q-rows per block (4 waves x 16)
#define BK  32      // k-cols per K-step

typedef __attribute__((ext_vector_type(8))) short bf16x8;
typedef __attribute__((ext_vector_type(4))) float f32x4;

__device__ __forceinline__ unsigned short f2b(float f) {
  union { float f; unsigned u; } x; x.f = f;
  unsigned r = x.u + 0x7fffu + ((x.u >> 16) & 1u);   // RNE
  return (unsigned short)(r >> 16);
}

// out = (sum_k !attn*e^s*V) / l  -  sum_k !attn*!alibi*d*bscale*V,  l = sum_k e^s
// One block: 64 q-rows, 4 waves x 16 rows, full F=128. K-loop BK=32.
__global__ __launch_bounds__(256, 2) void alibi_attn(
    const float* __restrict__ qp,
    const float* __restrict__ kp,
    const float* __restrict__ vp,
    const float* __restrict__ cqp,
    const float* __restrict__ ckp,
    const int* __restrict__ amp,
    const int* __restrict__ almp,
    const float* __restrict__ bsp,
    const float* __restrict__ rmp,
    float* __restrict__ outp)
{
  // kv: during prologue = Q tile bf16 [64][128] (16 KB);
  // in loop: K tile [32][128] at 0, V tile transposed [f=128][kr=32] at 4096
  __shared__ unsigned short kv[8192];
  // wave-private P/T buffers, row stride 40 shorts (80 B) to break bank alias
  __shared__ unsigned short plds[4][2][16 * 40];

  const int t    = threadIdx.x;
  const int w    = t >> 6;
  const int lane = t & 63;
  const int l15  = lane & 15;
  const int q4   = lane >> 4;          // quad 0..3

  // XCD-aware mapping: XCD x gets batches {2x, 2x+1}, all 32 q-tiles each
  const int bid  = blockIdx.x;
  const int xcd  = bid & 7, slot = bid >> 3;
  const int b    = (xcd << 1) | (slot >> 5);
  const int qt   = slot & 31;
  const int qbase = qt * BQ;

  const float bscale = bsp[0] / rmp[0];
  const float scale  = 0.08838834764831845f;   // 128^-0.5

  // ---- prologue: stage Q tile -> LDS bf16, grab A-frags + coords_q ----
  {
    const float* qg = qp + ((long long)(b * QL + qbase)) * FD;
    #pragma unroll
    for (int i = 0; i < 8; ++i) {
      float4 u = ((const float4*)qg)[t + 256 * i];
      ushort4 s4;
      s4.x = f2b(u.x); s4.y = f2b(u.y); s4.z = f2b(u.z); s4.w = f2b(u.w);
      *(ushort4*)&kv[(t + 256 * i) * 4] = s4;
    }
  }
  __syncthreads();
  bf16x8 qfrag[4];
  {
    const int m = w * 16 + l15;
    #pragma unroll
    for (int fs = 0; fs < 4; ++fs)
      qfrag[fs] = *(const bf16x8*)&kv[m * 128 + fs * 32 + q4 * 8];
  }
  float cqx[4], cqy[4];
  #pragma unroll
  for (int r = 0; r < 4; ++r) {
    const int qg_ = qbase + w * 16 + q4 * 4 + r;
    cqx[r] = cqp[((long long)(b * QL + qg_)) * 2 + 0];
    cqy[r] = cqp[((long long)(b * QL + qg_)) * 2 + 1];
  }
  __syncthreads();   // Q frag reads done before kv is overwritten

  f32x4 O1[8], O2[8];
  #pragma unroll
  for (int n = 0; n < 8; ++n) {
    O1[n] = (f32x4){0.f, 0.f, 0.f, 0.f};
    O2[n] = (f32x4){0.f, 0.f, 0.f, 0.f};
  }
  float lsum[4] = {0.f, 0.f, 0.f, 0.f};

  const int kr_st = t >> 3;          // staging row 0..31
  const int fb_st = (t & 7) * 16;    // staging f-base
  const float* kg_base = kp + ((long long)b * KL) * FD;
  const float* vg_base = vp + ((long long)b * KL) * FD;

  for (int kt = 0; kt < KL / BK; ++kt) {
    const int k0 = kt * BK;

    // global staging loads (issue before barrier; hide under prior PV + barrier)
    float4 kld[4], vld[4];
    #pragma unroll
    for (int i = 0; i < 4; ++i) {
      kld[i] = *(const float4*)(kg_base + (long long)(k0 + kr_st) * FD + fb_st + 4 * i);
      vld[i] = *(const float4*)(vg_base + (long long)(k0 + kr_st) * FD + fb_st + 4 * i);
    }
    // mask loads (nontemporal: 512 MB single-use stream) + coords_k
    int am_[2][4], al_[2][4];
    float ckx_[2], cky_[2];
    #pragma unroll
    for (int s = 0; s < 2; ++s) {
      const int kg = k0 + s * 16 + l15;
      #pragma unroll
      for (int r = 0; r < 4; ++r) {
        const int qg_ = qbase + w * 16 + q4 * 4 + r;
        const long long mi = ((long long)(b * QL + qg_)) * KL + kg;
        am_[s][r] = __builtin_nontemporal_load(amp + mi);
        al_[s][r] = __builtin_nontemporal_load(almp + mi);
      }
      float2 c2 = *(const float2*)(ckp + ((long long)(b * KL + kg)) * 2);
      ckx_[s] = c2.x; cky_[s] = c2.y;
    }

    __syncthreads();   // prior iteration's LDS reads complete
    // write K tile [kr][f] and V tile transposed [f][kr]
    #pragma unroll
    for (int i = 0; i < 4; ++i) {
      ushort4 s4;
      s4.x = f2b(kld[i].x); s4.y = f2b(kld[i].y);
      s4.z = f2b(kld[i].z); s4.w = f2b(kld[i].w);
      *(ushort4*)&kv[kr_st * 128 + fb_st + 4 * i] = s4;
      const int f0 = fb_st + 4 * i;
      kv[4096 + (f0 + 0) * 32 + kr_st] = f2b(vld[i].x);
      kv[4096 + (f0 + 1) * 32 + kr_st] = f2b(vld[i].y);
      kv[4096 + (f0 + 2) * 32 + kr_st] = f2b(vld[i].z);
      kv[4096 + (f0 + 3) * 32 + kr_st] = f2b(vld[i].w);
    }
    __syncthreads();

    // QK^T: two 16x16 S tiles over F=128
    f32x4 S0 = (f32x4){0.f, 0.f, 0.f, 0.f};
    f32x4 S1 = (f32x4){0.f, 0.f, 0.f, 0.f};
    #pragma unroll
    for (int fs = 0; fs < 4; ++fs) {
      bf16x8 kb0 = *(const bf16x8*)&kv[(l15)      * 128 + fs * 32 + q4 * 8];
      bf16x8 kb1 = *(const bf16x8*)&kv[(16 + l15) * 128 + fs * 32 + q4 * 8];
      S0 = __builtin_amdgcn_mfma_f32_16x16x32_bf16(qfrag[fs], kb0, S0, 0, 0, 0);
      S1 = __builtin_amdgcn_mfma_f32_16x16x32_bf16(qfrag[fs], kb1, S1, 0, 0, 0);
    }

    // transform: e=exp(s*scale); w=!attn*e; t=!attn*!alibi*dist*bscale
    #pragma unroll
    for (int s = 0; s < 2; ++s) {
      const f32x4 Sv = s ? S1 : S0;
      #pragma unroll
      for (int r = 0; r < 4; ++r) {
        float e = __expf(Sv[r] * scale);
        lsum[r] += e;
        float dx = cqx[r] - ckx_[s], dy = cqy[r] - cky_[s];
        float d  = sqrtf(fmaf(dx, dx, dy * dy)) * bscale;
        float wv = am_[s][r] ? 0.f : e;
        float tv = (am_[s][r] | al_[s][r]) ? 0.f : d;
        const int m = q4 * 4 + r, c = s * 16 + l15;
        plds[w][0][m * 40 + c] = f2b(wv);
        plds[w][1][m * 40 + c] = f2b(tv);
      }
    }
    __syncthreads();   // P write -> A-frag read (also spaces V reads)

    // PV: A-frags from P/T, B-frags from V^T LDS; dual accumulate
    bf16x8 aw = *(const bf16x8*)&plds[w][0][l15 * 40 + q4 * 8];
    bf16x8 at = *(const bf16x8*)&plds[w][1][l15 * 40 + q4 * 8];
    #pragma unroll
    for (int n = 0; n < 8; ++n) {
      bf16x8 vb = *(const bf16x8*)&kv[4096 + (n * 16 + l15) * 32 + q4 * 8];
      O1[n] = __builtin_amdgcn_mfma_f32_16x16x32_bf16(aw, vb, O1[n], 0, 0, 0);
      O2[n] = __builtin_amdgcn_mfma_f32_16x16x32_bf16(at, vb, O2[n], 0, 0, 0);
    }
  }

  // ---- epilogue: row sums across the 16 lanes of each quad, combine, store ----
  #pragma unroll
  for (int off = 1; off < 16; off <<= 1) {
    #pragma unroll
    for (int r = 0; r < 4; ++r) lsum[r] += __shfl_xor(lsum[r], off, 64);
  }
  float linv[4];
  #pragma unroll
  for (int r = 0; r < 4; ++r) linv[r] = 1.0f / lsum[r];

  #pragma unroll
  for (int n = 0; n < 8; ++n) {
    #pragma unroll
    for (int r = 0; r < 4; ++r) {
      const int qg_ = qbase + w * 16 + q4 * 4 + r;
      const int f   = n * 16 + l15;
      float val = O1[n][r] * linv[r] - O2[n][r];
      __builtin_nontemporal_store(val, outp + ((long long)(b * QL + qg_)) * FD + f);
    }
  }
}

extern "C" void kernel_launch(void* const* d_in, const int* in_sizes, int n_in,
                              void* d_out, int out_size, void* d_ws, size_t ws_size,
                              hipStream_t stream) {
  const float* q   = (const float*)d_in[0];
  const float* k   = (const float*)d_in[1];
  const float* v   = (const float*)d_in[2];
  const float* cq  = (const float*)d_in[3];
  const float* ck  = (const float*)d_in[4];
  const int*   am  = (const int*)d_in[5];
  const int*   alm = (const int*)d_in[6];
  const float* bs  = (const float*)d_in[7];
  const float* rm  = (const float*)d_in[8];
  float*       out = (float*)d_out;

  dim3 grid(B_ * (QL / BQ));   // 512 blocks, 2 per CU
  dim3 block(256);
  hipLaunchKernelGGL(alibi_attn, grid, block, 0, stream,
                     q, k, v, cq, ck, am, alm, bs, rm, out);
}

// Round 5
// 676.214 us; speedup vs baseline: 3.3774x; 1.1120x over previous
//
#include <hip/hip_runtime.h>
#include <stdint.h>

#define B_  16
#define QL  2048
#define KL  2048
#define FD  128
#define BQ  64
#define BK  32
#define NSTEP (KL/BK)

#define KSTR  136      // K-tile row stride in shorts (272 B: b128 reads land 2-way max)
#define VTOFF 4352     // 32*136
#define VTSTR 40       // V^T row stride in shorts (80 B)
#define BUFSHORTS 9472 // 4352 + 128*40
#define PSTR  40

typedef __attribute__((ext_vector_type(8))) short bf16x8;
typedef __attribute__((ext_vector_type(4))) float f32x4;

__device__ __forceinline__ unsigned short f2b(float f) {
  union { float f; unsigned u; } x; x.f = f;
  return (unsigned short)((x.u + 0x8000u) >> 16);   // round-to-nearest, 2 ops
}

// out = (sum_k !attn*e^s*V)/l - sum_k !attn*!alibi*d*bscale*V,  l = sum_k e^s
// 64 q-rows/block, 4 waves x 16 rows. BK=32 K-steps, double-buffered LDS,
// ONE barrier per step, all global loads prefetched a full iteration ahead.
__global__ __launch_bounds__(256, 2) void alibi_attn(
    const float* __restrict__ qp,
    const float* __restrict__ kp,
    const float* __restrict__ vp,
    const float* __restrict__ cqp,
    const float* __restrict__ ckp,
    const int* __restrict__ amp,
    const int* __restrict__ almp,
    const float* __restrict__ bsp,
    const float* __restrict__ rmp,
    float* __restrict__ outp)
{
  __shared__ unsigned short kv[2 * BUFSHORTS];       // 37 KB, K + V^T double buffer
  __shared__ unsigned short plds[4][2][16 * PSTR];   // 10 KB, wave-private P/T

  const int t    = threadIdx.x;
  const int w    = t >> 6;
  const int lane = t & 63;
  const int l15  = lane & 15;
  const int q4   = lane >> 4;

  const int bid  = blockIdx.x;
  const int xcd  = bid & 7, slot = bid >> 3;
  const int b    = (xcd << 1) | (slot >> 5);
  const int qbase = (slot & 31) * BQ;

  const float bscale = bsp[0] / rmp[0];
  const float sl2 = 0.08838834764831845f * 1.44269504089f;  // scale*log2(e)

  const int kr_st = t >> 3;          // staging k-row 0..31
  const int fb_st = (t & 7) * 4;     // f = fb_st + 32*i (+d): 128B-coalesced, spreads VT banks

  // ---- prologue: Q tile -> LDS bf16 (stride KSTR), read A-frags + coords_q ----
  {
    const float* qg = qp + ((long long)(b * QL + qbase)) * FD;
    #pragma unroll
    for (int i = 0; i < 8; ++i) {
      int idx = t + 256 * i;
      float4 u = ((const float4*)qg)[idx];
      int row = idx >> 5, col = (idx & 31) * 4;
      ushort4 s4; s4.x = f2b(u.x); s4.y = f2b(u.y); s4.z = f2b(u.z); s4.w = f2b(u.w);
      *(ushort4*)&kv[row * KSTR + col] = s4;
    }
  }
  __syncthreads();
  bf16x8 qfrag[4];
  {
    const int m = w * 16 + l15;
    #pragma unroll
    for (int fs = 0; fs < 4; ++fs)
      qfrag[fs] = *(const bf16x8*)&kv[m * KSTR + fs * 32 + q4 * 8];
  }
  float cqx[4], cqy[4];
  long long mrow_base[4];
  #pragma unroll
  for (int r = 0; r < 4; ++r) {
    const int qg_ = qbase + w * 16 + q4 * 4 + r;
    float2 c2 = *(const float2*)(cqp + ((long long)(b * QL + qg_)) * 2);
    cqx[r] = c2.x; cqy[r] = c2.y;
    mrow_base[r] = ((long long)(b * QL + qg_)) * KL;
  }
  __syncthreads();   // Q-frag reads done before buf0 is overwritten

  const float* kgb = kp + ((long long)b * KL) * FD;
  const float* vgb = vp + ((long long)b * KL) * FD;

  // ---- preload masks/coords for kt=0; stage K/V tile 0 into buf0 ----
  int am_b[2][2][4], al_b[2][2][4];
  float ckx_b[2][2], cky_b[2][2];
  #pragma unroll
  for (int s = 0; s < 2; ++s) {
    const int kg = s * 16 + l15;
    #pragma unroll
    for (int r = 0; r < 4; ++r) {
      am_b[0][s][r] = __builtin_nontemporal_load(amp + mrow_base[r] + kg);
      al_b[0][s][r] = __builtin_nontemporal_load(almp + mrow_base[r] + kg);
    }
    float2 c2 = *(const float2*)(ckp + ((long long)(b * KL + kg)) * 2);
    ckx_b[0][s] = c2.x; cky_b[0][s] = c2.y;
  }
  {
    float4 kld[4], vld[4];
    #pragma unroll
    for (int i = 0; i < 4; ++i) {
      kld[i] = *(const float4*)(kgb + (long long)kr_st * FD + fb_st + 32 * i);
      vld[i] = *(const float4*)(vgb + (long long)kr_st * FD + fb_st + 32 * i);
    }
    #pragma unroll
    for (int i = 0; i < 4; ++i) {
      ushort4 s4; s4.x = f2b(kld[i].x); s4.y = f2b(kld[i].y);
      s4.z = f2b(kld[i].z); s4.w = f2b(kld[i].w);
      *(ushort4*)&kv[kr_st * KSTR + fb_st + 32 * i] = s4;
      const int f0 = fb_st + 32 * i;
      kv[VTOFF + (f0 + 0) * VTSTR + kr_st] = f2b(vld[i].x);
      kv[VTOFF + (f0 + 1) * VTSTR + kr_st] = f2b(vld[i].y);
      kv[VTOFF + (f0 + 2) * VTSTR + kr_st] = f2b(vld[i].z);
      kv[VTOFF + (f0 + 3) * VTSTR + kr_st] = f2b(vld[i].w);
    }
  }
  __syncthreads();

  f32x4 O1[8], O2[8];
  #pragma unroll
  for (int n = 0; n < 8; ++n) {
    O1[n] = (f32x4){0.f, 0.f, 0.f, 0.f};
    O2[n] = (f32x4){0.f, 0.f, 0.f, 0.f};
  }
  float lsum[4] = {0.f, 0.f, 0.f, 0.f};

  #pragma unroll 2
  for (int kt = 0; kt < NSTEP; ++kt) {
    const int cur = kt & 1, nxt = cur ^ 1;
    const unsigned short* kb = kv + cur * BUFSHORTS;
    unsigned short*       nb = kv + nxt * BUFSHORTS;
    const int ktp = (kt + 1 < NSTEP) ? (kt + 1) : kt;   // clamp last prefetch
    const int k0p = ktp * BK;

    // ---- prefetch next step's K/V + masks + coords (consumed after 1 barrier) ----
    float4 kld[4], vld[4];
    #pragma unroll
    for (int i = 0; i < 4; ++i) {
      kld[i] = *(const float4*)(kgb + (long long)(k0p + kr_st) * FD + fb_st + 32 * i);
      vld[i] = *(const float4*)(vgb + (long long)(k0p + kr_st) * FD + fb_st + 32 * i);
    }
    #pragma unroll
    for (int s = 0; s < 2; ++s) {
      const int kg = k0p + s * 16 + l15;
      #pragma unroll
      for (int r = 0; r < 4; ++r) {
        am_b[nxt][s][r] = __builtin_nontemporal_load(amp + mrow_base[r] + kg);
        al_b[nxt][s][r] = __builtin_nontemporal_load(almp + mrow_base[r] + kg);
      }
      float2 c2 = *(const float2*)(ckp + ((long long)(b * KL + kg)) * 2);
      ckx_b[nxt][s] = c2.x; cky_b[nxt][s] = c2.y;
    }

    // ---- QK^T over F=128 ----
    f32x4 S0 = (f32x4){0.f, 0.f, 0.f, 0.f};
    f32x4 S1 = (f32x4){0.f, 0.f, 0.f, 0.f};
    #pragma unroll
    for (int fs = 0; fs < 4; ++fs) {
      bf16x8 kb0 = *(const bf16x8*)&kb[(l15)      * KSTR + fs * 32 + q4 * 8];
      bf16x8 kb1 = *(const bf16x8*)&kb[(16 + l15) * KSTR + fs * 32 + q4 * 8];
      S0 = __builtin_amdgcn_mfma_f32_16x16x32_bf16(qfrag[fs], kb0, S0, 0, 0, 0);
      S1 = __builtin_amdgcn_mfma_f32_16x16x32_bf16(qfrag[fs], kb1, S1, 0, 0, 0);
    }

    // ---- transform -> plds (wave-private; masks prefetched last iter) ----
    #pragma unroll
    for (int s = 0; s < 2; ++s) {
      const f32x4 Sv = s ? S1 : S0;
      #pragma unroll
      for (int r = 0; r < 4; ++r) {
        float e = __builtin_amdgcn_exp2f(Sv[r] * sl2);
        lsum[r] += e;
        float dx = cqx[r] - ckx_b[cur][s], dy = cqy[r] - cky_b[cur][s];
        float d  = sqrtf(fmaf(dx, dx, dy * dy)) * bscale;
        int am = am_b[cur][s][r], al = al_b[cur][s][r];
        float wv = am ? 0.f : e;
        float tv = (am | al) ? 0.f : d;
        const int mm = q4 * 4 + r, c = s * 16 + l15;
        plds[w][0][mm * PSTR + c] = f2b(wv);
        plds[w][1][mm * PSTR + c] = f2b(tv);
      }
    }

    // ---- PV: all reads of cur buffer complete BEFORE the barrier ----
    bf16x8 aw = *(const bf16x8*)&plds[w][0][l15 * PSTR + q4 * 8];
    bf16x8 at = *(const bf16x8*)&plds[w][1][l15 * PSTR + q4 * 8];
    #pragma unroll
    for (int n = 0; n < 8; ++n) {
      bf16x8 vb = *(const bf16x8*)&kb[VTOFF + (n * 16 + l15) * VTSTR + q4 * 8];
      O1[n] = __builtin_amdgcn_mfma_f32_16x16x32_bf16(aw, vb, O1[n], 0, 0, 0);
      O2[n] = __builtin_amdgcn_mfma_f32_16x16x32_bf16(at, vb, O2[n], 0, 0, 0);
    }

    // ---- stage next K/V into nxt buffer, single barrier ----
    #pragma unroll
    for (int i = 0; i < 4; ++i) {
      ushort4 s4; s4.x = f2b(kld[i].x); s4.y = f2b(kld[i].y);
      s4.z = f2b(kld[i].z); s4.w = f2b(kld[i].w);
      *(ushort4*)&nb[kr_st * KSTR + fb_st + 32 * i] = s4;
      const int f0 = fb_st + 32 * i;
      nb[VTOFF + (f0 + 0) * VTSTR + kr_st] = f2b(vld[i].x);
      nb[VTOFF + (f0 + 1) * VTSTR + kr_st] = f2b(vld[i].y);
      nb[VTOFF + (f0 + 2) * VTSTR + kr_st] = f2b(vld[i].z);
      nb[VTOFF + (f0 + 3) * VTSTR + kr_st] = f2b(vld[i].w);
    }
    __syncthreads();
  }

  // ---- epilogue: reduce lsum over 16 lanes (within quad rows), combine, store ----
  #pragma unroll
  for (int off = 1; off < 16; off <<= 1) {
    #pragma unroll
    for (int r = 0; r < 4; ++r) lsum[r] += __shfl_xor(lsum[r], off, 64);
  }
  float linv[4];
  #pragma unroll
  for (int r = 0; r < 4; ++r) linv[r] = 1.0f / lsum[r];

  #pragma unroll
  for (int n = 0; n < 8; ++n) {
    #pragma unroll
    for (int r = 0; r < 4; ++r) {
      const int qg_ = qbase + w * 16 + q4 * 4 + r;
      const int f   = n * 16 + l15;
      float val = O1[n][r] * linv[r] - O2[n][r];
      __builtin_nontemporal_store(val, outp + ((long long)(b * QL + qg_)) * FD + f);
    }
  }
}

extern "C" void kernel_launch(void* const* d_in, const int* in_sizes, int n_in,
                              void* d_out, int out_size, void* d_ws, size_t ws_size,
                              hipStream_t stream) {
  const float* q   = (const float*)d_in[0];
  const float* k   = (const float*)d_in[1];
  const float* v   = (const float*)d_in[2];
  const float* cq  = (const float*)d_in[3];
  const float* ck  = (const float*)d_in[4];
  const int*   am  = (const int*)d_in[5];
  const int*   alm = (const int*)d_in[6];
  const float* bs  = (const float*)d_in[7];
  const float* rm  = (const float*)d_in[8];
  float*       out = (float*)d_out;

  dim3 grid(B_ * (QL / BQ));   // 512 blocks, 2/CU
  dim3 block(256);
  hipLaunchKernelGGL(alibi_attn, grid, block, 0, stream,
                     q, k, v, cq, ck, am, alm, bs, rm, out);
}